// Round 9
// baseline (509.331 us; speedup 1.0000x reference)
//
#include <hip/hip_runtime.h>

// YOLO-style loss, B=131072, GRID=7, CELLS=49, 11 floats/cell.
// R2: non-atomic partial reduction (77us). R3: occupancy CPC=512 (58.2us) BEST.
// R4: persistent pipeline regressed (62.7). R5: algebraic split (59.5).
// R7: dense float4 minimal stream (62.6). Three disjoint structures converge
//     at 58-63us -> fetch-path ceiling ~5.1 TB/s effective. Compute/LDS/issue
//     are not the wall.
// R8: R3 verbatim + fused reduction (last-block-done with device-scope fence
//     + atomic ticket; final block sums partials). Removes the second kernel
//     launch + serialization (~3-6us). If this doesn't beat 58us, R3 is the
//     practical floor -> ROOFLINE.

constexpr int BLOCK = 256;
constexpr int CPC = 512;                        // cells per chunk (per block)
constexpr int FLOATS_PER_CHUNK = CPC * 11;      // 5632
constexpr int F4_PER_CHUNK = FLOATS_PER_CHUNK / 4;  // 1408 = 5.5 * 256
constexpr int TOTAL_CELLS = 131072 * 49;        // 6422528
constexpr int NCHUNKS = TOTAL_CELLS / CPC;      // 12544 (exact)

__global__ __launch_bounds__(BLOCK) void yolo_loss_kernel(
    const float* __restrict__ outputs,
    const float* __restrict__ target,
    double* __restrict__ part,
    unsigned* __restrict__ ticket,
    float* __restrict__ out)
{
#pragma clang fp contract(off)
    __shared__ float lds[FLOATS_PER_CHUNK];     // 22528 B
    __shared__ double wred[BLOCK / 64];
    __shared__ bool is_last;

    const int t = threadIdx.x;
    const unsigned chunk = blockIdx.x;

    // ---- stage 512 cells (1408 float4) into LDS: 5 full rounds + half round
    const float4* src = reinterpret_cast<const float4*>(outputs)
                        + (size_t)chunk * F4_PER_CHUNK;
    float4* l4 = reinterpret_cast<float4*>(lds);
#pragma unroll
    for (int i = 0; i < 5; ++i)
        l4[t + BLOCK * i] = src[t + BLOCK * i];
    if (t < 128)                                 // wave-aligned half round
        l4[t + 1280] = src[t + 1280];
    __syncthreads();

    const float4* tg4 = reinterpret_cast<const float4*>(target);
    const float CW = 1.0f / 7.0f;

    double a = 0.0;
#pragma unroll
    for (int q = 0; q < 2; ++q) {
        const int cl = t + BLOCK * q;               // cell within chunk
        const unsigned g = chunk * CPC + cl;        // global cell index
        const unsigned b = g / 49u;                 // sample
        const unsigned s = g - b * 49u;             // cell within sample
        const float xl = (float)(s % 7u) / 7.0f;    // exact fp32 div, matches numpy
        const float yl = (float)(s / 7u) / 7.0f;

        const float4 T0 = tg4[2u * b];
        const float4 T1 = tg4[2u * b + 1u];
        const bool v1 = (T1.x != -1.0f);

        const float* cp = lds + cl * 11;            // 11t base: coprime w/ 32 banks

        float conf0, conf1, term0, term1;
        bool one0, one1;
        {   // box j=0 (always valid)
            const float px = cp[0], py = cp[1], pw = cp[2], ph = cp[3], pc = cp[4];
            const float tx = T0.x, ty = T0.y, tw = T0.z, th = T0.w;
            const float ix = fabsf(fmaxf(px - 0.5f * pw, tx - 0.5f * tw)
                                 - fminf(px + 0.5f * pw, tx + 0.5f * tw));
            const float iy = fabsf(fmaxf(py - 0.5f * ph, ty - 0.5f * th)
                                 - fminf(py + 0.5f * ph, ty + 0.5f * th));
            const float inter = ix * iy;
            const float uni = pw * ph + tw * th - inter;
            conf0 = inter / uni;
            one0 = (xl <= tx) && (tx <= xl + CW) && (yl <= ty) && (ty <= yl + CW);
            const float d0 = tx - px, d1 = ty - py;
            const float d2 = sqrtf(tw) - sqrtf(pw);
            const float d3 = sqrtf(th) - sqrtf(ph);
            const float coord = ((d0 * d0 + d1 * d1) + d2 * d2) + d3 * d3;
            const float dc = conf0 - pc;
            term0 = one0 ? (5.0f * coord + dc * dc) : (0.5f * pc * pc);
        }
        {   // box j=1 (valid iff T1.x != -1)
            const float px = cp[5], py = cp[6], pw = cp[7], ph = cp[8], pc = cp[9];
            const float tx = T1.x, ty = T1.y, tw = T1.z, th = T1.w;
            const float ix = fabsf(fmaxf(px - 0.5f * pw, tx - 0.5f * tw)
                                 - fminf(px + 0.5f * pw, tx + 0.5f * tw));
            const float iy = fabsf(fmaxf(py - 0.5f * ph, ty - 0.5f * th)
                                 - fminf(py + 0.5f * ph, ty + 0.5f * th));
            const float inter = ix * iy;
            const float uni = pw * ph + tw * th - inter;
            conf1 = inter / uni;
            const bool inx = (xl <= tx) && (tx <= xl + CW);
            const bool iny = (yl <= ty) && (ty <= yl + CW);
            one1 = inx && iny && v1;
            const float d0 = tx - px, d1 = ty - py;
            const float d2 = sqrtf(tw) - sqrtf(pw);
            const float d3 = sqrtf(th) - sqrtf(ph);
            const float coord = ((d0 * d0 + d1 * d1) + d2 * d2) + d3 * d3;
            const float dc = conf1 - pc;
            term1 = one1 ? (5.0f * coord + dc * dc)
                         : (v1 ? (0.5f * pc * pc) : 0.0f);
        }
        // class term
        const float sum_conf = conf0 + (v1 ? conf1 : 0.0f);
        float cls = 0.0f;
        if (one0 || one1) {
            const float d = cp[10] - sum_conf;
            cls = d * d;
        }
        a += (double)term0 + (double)term1 + (double)cls;
    }

    // ---- block partial -> d_ws
#pragma unroll
    for (int off = 32; off > 0; off >>= 1)
        a += __shfl_down(a, off);
    if ((t & 63) == 0) wred[t >> 6] = a;
    __syncthreads();
    if (t == 0) {
        part[chunk] = wred[0] + wred[1] + wred[2] + wred[3];
        __threadfence();                         // publish partial (device scope)
        const unsigned prev = atomicAdd(ticket, 1u);
        is_last = (prev == (unsigned)NCHUNKS - 1u);
    }
    __syncthreads();

    // ---- last finishing block reduces all partials (fixed order: by index)
    if (is_last) {
        __threadfence();                         // acquire all partials
        double r = 0.0;
        for (int i = t; i < NCHUNKS; i += BLOCK)
            r += part[i];
#pragma unroll
        for (int off = 32; off > 0; off >>= 1)
            r += __shfl_down(r, off);
        if ((t & 63) == 0) wred[t >> 6] = r;
        __syncthreads();
        if (t == 0)
            out[0] = (float)(wred[0] + wred[1] + wred[2] + wred[3]);
    }
}

extern "C" void kernel_launch(void* const* d_in, const int* in_sizes, int n_in,
                              void* d_out, int out_size, void* d_ws, size_t ws_size,
                              hipStream_t stream)
{
    const float* outputs = (const float*)d_in[0];
    const float* target  = (const float*)d_in[1];
    float* out = (float*)d_out;
    double* part = (double*)d_ws;                    // NCHUNKS doubles = 100352 B
    unsigned* ticket = (unsigned*)((char*)d_ws + NCHUNKS * sizeof(double));

    hipMemsetAsync(ticket, 0, sizeof(unsigned), stream);
    yolo_loss_kernel<<<NCHUNKS, BLOCK, 0, stream>>>(outputs, target, part,
                                                    ticket, out);
}

// Round 10
// 62.264 us; speedup vs baseline: 8.1802x; 8.1802x over previous
//
#include <hip/hip_runtime.h>

// YOLO-style loss, B=131072, GRID=7, CELLS=49, 11 floats/cell.
// R2: partial-store reduction (77us). R3: CPC=512, 28 waves/CU (58.2us) BEST.
// R4: persistent pipeline regressed (62.7). R5: algebraic split (59.5).
// R7: dense float4 stream (62.6). -> three structures converge: fetch-path
//     ceiling ~5.1 TB/s effective (137MB HBM + ~146MB L3 per pass).
// R8: last-block-done fused reduce CATASTROPHIC (509us): 12544 device-scope
//     fences+atomic tickets stall the machine. NEVER do per-block
//     __threadfence() on this chip; 1-block second kernel costs only ~3us.
// R10: R3 structure verbatim, CPC 512->256 (LDS 11.3KB): 8 blocks/CU,
//      32 waves/CU (hw max), half the per-block stage->barrier chain.
//      Last occupancy lever; if neutral, R3/R10 is the roofline.

constexpr int BLOCK = 256;
constexpr int CPC = 256;                        // cells per chunk (per block)
constexpr int FLOATS_PER_CHUNK = CPC * 11;      // 2816
constexpr int F4C = FLOATS_PER_CHUNK / 4;       // 704 = 2.75 * 256
constexpr int TOTAL_CELLS = 131072 * 49;        // 6422528
constexpr int NCHUNKS = TOTAL_CELLS / CPC;      // 25088 (exact)

__global__ __launch_bounds__(BLOCK) void yolo_loss_kernel(
    const float* __restrict__ outputs,
    const float* __restrict__ target,
    double* __restrict__ part)
{
#pragma clang fp contract(off)
    __shared__ float lds[FLOATS_PER_CHUNK];     // 11264 B
    __shared__ double wred[BLOCK / 64];

    const int t = threadIdx.x;
    const unsigned chunk = blockIdx.x;

    // ---- stage 256 cells (704 float4): 2 full rounds + 192-lane round
    const float4* src = reinterpret_cast<const float4*>(outputs)
                        + (size_t)chunk * F4C;
    float4* l4 = reinterpret_cast<float4*>(lds);
    l4[t] = src[t];
    l4[t + 256] = src[t + 256];
    if (t < 192)                                 // 3 full waves
        l4[t + 512] = src[t + 512];
    __syncthreads();

    const float4* tg4 = reinterpret_cast<const float4*>(target);
    const float CW = 1.0f / 7.0f;

    double a = 0.0;
    {
        const int cl = t;                           // 1 cell per thread
        const unsigned g = chunk * CPC + cl;        // global cell index
        const unsigned b = g / 49u;                 // sample
        const unsigned s = g - b * 49u;             // cell within sample
        const float xl = (float)(s % 7u) / 7.0f;    // exact fp32 div, matches numpy
        const float yl = (float)(s / 7u) / 7.0f;

        const float4 T0 = tg4[2u * b];
        const float4 T1 = tg4[2u * b + 1u];
        const bool v1 = (T1.x != -1.0f);

        const float* cp = lds + cl * 11;            // 11t base: coprime w/ 32 banks

        float conf0, conf1, term0, term1;
        bool one0, one1;
        {   // box j=0 (always valid)
            const float px = cp[0], py = cp[1], pw = cp[2], ph = cp[3], pc = cp[4];
            const float tx = T0.x, ty = T0.y, tw = T0.z, th = T0.w;
            const float ix = fabsf(fmaxf(px - 0.5f * pw, tx - 0.5f * tw)
                                 - fminf(px + 0.5f * pw, tx + 0.5f * tw));
            const float iy = fabsf(fmaxf(py - 0.5f * ph, ty - 0.5f * th)
                                 - fminf(py + 0.5f * ph, ty + 0.5f * th));
            const float inter = ix * iy;
            const float uni = pw * ph + tw * th - inter;
            conf0 = inter / uni;
            one0 = (xl <= tx) && (tx <= xl + CW) && (yl <= ty) && (ty <= yl + CW);
            const float d0 = tx - px, d1 = ty - py;
            const float d2 = sqrtf(tw) - sqrtf(pw);
            const float d3 = sqrtf(th) - sqrtf(ph);
            const float coord = ((d0 * d0 + d1 * d1) + d2 * d2) + d3 * d3;
            const float dc = conf0 - pc;
            term0 = one0 ? (5.0f * coord + dc * dc) : (0.5f * pc * pc);
        }
        {   // box j=1 (valid iff T1.x != -1)
            const float px = cp[5], py = cp[6], pw = cp[7], ph = cp[8], pc = cp[9];
            const float tx = T1.x, ty = T1.y, tw = T1.z, th = T1.w;
            const float ix = fabsf(fmaxf(px - 0.5f * pw, tx - 0.5f * tw)
                                 - fminf(px + 0.5f * pw, tx + 0.5f * tw));
            const float iy = fabsf(fmaxf(py - 0.5f * ph, ty - 0.5f * th)
                                 - fminf(py + 0.5f * ph, ty + 0.5f * th));
            const float inter = ix * iy;
            const float uni = pw * ph + tw * th - inter;
            conf1 = inter / uni;
            const bool inx = (xl <= tx) && (tx <= xl + CW);
            const bool iny = (yl <= ty) && (ty <= yl + CW);
            one1 = inx && iny && v1;
            const float d0 = tx - px, d1 = ty - py;
            const float d2 = sqrtf(tw) - sqrtf(pw);
            const float d3 = sqrtf(th) - sqrtf(ph);
            const float coord = ((d0 * d0 + d1 * d1) + d2 * d2) + d3 * d3;
            const float dc = conf1 - pc;
            term1 = one1 ? (5.0f * coord + dc * dc)
                         : (v1 ? (0.5f * pc * pc) : 0.0f);
        }
        // class term
        const float sum_conf = conf0 + (v1 ? conf1 : 0.0f);
        float cls = 0.0f;
        if (one0 || one1) {
            const float d = cp[10] - sum_conf;
            cls = d * d;
        }
        a = (double)term0 + (double)term1 + (double)cls;
    }

    // ---- reduction: wave shfl -> LDS -> block partial -> d_ws (NO atomics)
#pragma unroll
    for (int off = 32; off > 0; off >>= 1)
        a += __shfl_down(a, off);
    if ((t & 63) == 0) wred[t >> 6] = a;
    __syncthreads();
    if (t == 0)
        part[chunk] = wred[0] + wred[1] + wred[2] + wred[3];
}

constexpr int RBLOCK = 1024;
__global__ __launch_bounds__(RBLOCK) void reduce_kernel(
    const double* __restrict__ part, float* __restrict__ out)
{
    __shared__ double wred[RBLOCK / 64];
    const int t = threadIdx.x;
    double a = 0.0;
    for (int i = t; i < NCHUNKS; i += RBLOCK)
        a += part[i];
#pragma unroll
    for (int off = 32; off > 0; off >>= 1)
        a += __shfl_down(a, off);
    if ((t & 63) == 0) wred[t >> 6] = a;
    __syncthreads();
    if (t == 0) {
        double s = 0.0;
#pragma unroll
        for (int i = 0; i < RBLOCK / 64; ++i) s += wred[i];
        out[0] = (float)s;
    }
}

extern "C" void kernel_launch(void* const* d_in, const int* in_sizes, int n_in,
                              void* d_out, int out_size, void* d_ws, size_t ws_size,
                              hipStream_t stream)
{
    const float* outputs = (const float*)d_in[0];
    const float* target  = (const float*)d_in[1];
    float* out = (float*)d_out;
    double* part = (double*)d_ws;   // NCHUNKS doubles = 200704 B

    yolo_loss_kernel<<<NCHUNKS, BLOCK, 0, stream>>>(outputs, target, part);
    reduce_kernel<<<1, RBLOCK, 0, stream>>>(part, out);
}

// Round 11
// 61.457 us; speedup vs baseline: 8.2876x; 1.0131x over previous
//
#include <hip/hip_runtime.h>

// YOLO-style loss, B=131072, GRID=7, CELLS=49, 11 floats/cell.
// R2: partial-store reduction (77us). R3: CPC=512, 28 waves/CU (58.2us) BEST.
// R4: persistent pipeline 62.7. R5: algebraic split 59.5. R7: dense f4 62.6.
// R8: last-block-done fused reduce CATASTROPHIC (509us; per-block device
//     fences). R10: CPC=256 regressed (62.3) -> occupancy curve has its
//     minimum at CPC=512.
// Model: both endpoints underutilized (HBM 2.7/6.8 TB/s, VALU 30%, LDS 0
//     conflicts) -> bound by per-CU outstanding-load capacity x ~600ns miss
//     latency. In-flight bytes/CU correlates with all 5 prior results.
// R11: R3 verbatim BUT staging via global_load_lds (16B) - LDS-DMA queue is
//     separate from the VGPR load-return path (cp.async analog), and kills
//     5.5 ds_write/thread. R1 proved this staging correct (atomic-masked).

constexpr int BLOCK = 256;
constexpr int CPC = 512;                        // cells per chunk (per block)
constexpr int FLOATS_PER_CHUNK = CPC * 11;      // 5632
constexpr int F4C = FLOATS_PER_CHUNK / 4;       // 1408 = 5.5 * 256
constexpr int TOTAL_CELLS = 131072 * 49;        // 6422528
constexpr int NCHUNKS = TOTAL_CELLS / CPC;      // 12544 (exact)

__global__ __launch_bounds__(BLOCK) void yolo_loss_kernel(
    const float* __restrict__ outputs,
    const float* __restrict__ target,
    double* __restrict__ part)
{
#pragma clang fp contract(off)
    __shared__ float4 ldsv[F4C];                // 22528 B
    __shared__ double wred[BLOCK / 64];

    const int t = threadIdx.x;
    const unsigned chunk = blockIdx.x;

    // ---- stage 512 cells (1408 float4) via LDS-DMA (global_load_lds, 16B).
    // LDS dest = wave-uniform base + lane*16 (linear) as required.
    const float4* src = reinterpret_cast<const float4*>(outputs)
                        + (size_t)chunk * F4C;
#pragma unroll
    for (int i = 0; i < 5; ++i) {
        __builtin_amdgcn_global_load_lds(
            (const __attribute__((address_space(1))) void*)(src + t + BLOCK * i),
            (__attribute__((address_space(3))) void*)(ldsv + t + BLOCK * i),
            16, 0, 0);
    }
    if (t < 128) {                               // wave-aligned half round
        __builtin_amdgcn_global_load_lds(
            (const __attribute__((address_space(1))) void*)(src + t + 1280),
            (__attribute__((address_space(3))) void*)(ldsv + t + 1280),
            16, 0, 0);
    }
    __syncthreads();                             // compiler drains vmcnt first

    const float* lds = reinterpret_cast<const float*>(ldsv);
    const float4* tg4 = reinterpret_cast<const float4*>(target);
    const float CW = 1.0f / 7.0f;

    double a = 0.0;
#pragma unroll
    for (int q = 0; q < 2; ++q) {
        const int cl = t + BLOCK * q;               // cell within chunk
        const unsigned g = chunk * CPC + cl;        // global cell index
        const unsigned b = g / 49u;                 // sample
        const unsigned s = g - b * 49u;             // cell within sample
        const float xl = (float)(s % 7u) / 7.0f;    // exact fp32 div, matches numpy
        const float yl = (float)(s / 7u) / 7.0f;

        const float4 T0 = tg4[2u * b];
        const float4 T1 = tg4[2u * b + 1u];
        const bool v1 = (T1.x != -1.0f);

        const float* cp = lds + cl * 11;            // 11t base: coprime w/ 32 banks

        float conf0, conf1, term0, term1;
        bool one0, one1;
        {   // box j=0 (always valid)
            const float px = cp[0], py = cp[1], pw = cp[2], ph = cp[3], pc = cp[4];
            const float tx = T0.x, ty = T0.y, tw = T0.z, th = T0.w;
            const float ix = fabsf(fmaxf(px - 0.5f * pw, tx - 0.5f * tw)
                                 - fminf(px + 0.5f * pw, tx + 0.5f * tw));
            const float iy = fabsf(fmaxf(py - 0.5f * ph, ty - 0.5f * th)
                                 - fminf(py + 0.5f * ph, ty + 0.5f * th));
            const float inter = ix * iy;
            const float uni = pw * ph + tw * th - inter;
            conf0 = inter / uni;
            one0 = (xl <= tx) && (tx <= xl + CW) && (yl <= ty) && (ty <= yl + CW);
            const float d0 = tx - px, d1 = ty - py;
            const float d2 = sqrtf(tw) - sqrtf(pw);
            const float d3 = sqrtf(th) - sqrtf(ph);
            const float coord = ((d0 * d0 + d1 * d1) + d2 * d2) + d3 * d3;
            const float dc = conf0 - pc;
            term0 = one0 ? (5.0f * coord + dc * dc) : (0.5f * pc * pc);
        }
        {   // box j=1 (valid iff T1.x != -1)
            const float px = cp[5], py = cp[6], pw = cp[7], ph = cp[8], pc = cp[9];
            const float tx = T1.x, ty = T1.y, tw = T1.z, th = T1.w;
            const float ix = fabsf(fmaxf(px - 0.5f * pw, tx - 0.5f * tw)
                                 - fminf(px + 0.5f * pw, tx + 0.5f * tw));
            const float iy = fabsf(fmaxf(py - 0.5f * ph, ty - 0.5f * th)
                                 - fminf(py + 0.5f * ph, ty + 0.5f * th));
            const float inter = ix * iy;
            const float uni = pw * ph + tw * th - inter;
            conf1 = inter / uni;
            const bool inx = (xl <= tx) && (tx <= xl + CW);
            const bool iny = (yl <= ty) && (ty <= yl + CW);
            one1 = inx && iny && v1;
            const float d0 = tx - px, d1 = ty - py;
            const float d2 = sqrtf(tw) - sqrtf(pw);
            const float d3 = sqrtf(th) - sqrtf(ph);
            const float coord = ((d0 * d0 + d1 * d1) + d2 * d2) + d3 * d3;
            const float dc = conf1 - pc;
            term1 = one1 ? (5.0f * coord + dc * dc)
                         : (v1 ? (0.5f * pc * pc) : 0.0f);
        }
        // class term
        const float sum_conf = conf0 + (v1 ? conf1 : 0.0f);
        float cls = 0.0f;
        if (one0 || one1) {
            const float d = cp[10] - sum_conf;
            cls = d * d;
        }
        a += (double)term0 + (double)term1 + (double)cls;
    }

    // ---- reduction: wave shfl -> LDS -> block partial -> d_ws (NO atomics)
#pragma unroll
    for (int off = 32; off > 0; off >>= 1)
        a += __shfl_down(a, off);
    if ((t & 63) == 0) wred[t >> 6] = a;
    __syncthreads();
    if (t == 0)
        part[chunk] = wred[0] + wred[1] + wred[2] + wred[3];
}

constexpr int RBLOCK = 1024;
__global__ __launch_bounds__(RBLOCK) void reduce_kernel(
    const double* __restrict__ part, float* __restrict__ out)
{
    __shared__ double wred[RBLOCK / 64];
    const int t = threadIdx.x;
    double a = 0.0;
    for (int i = t; i < NCHUNKS; i += RBLOCK)
        a += part[i];
#pragma unroll
    for (int off = 32; off > 0; off >>= 1)
        a += __shfl_down(a, off);
    if ((t & 63) == 0) wred[t >> 6] = a;
    __syncthreads();
    if (t == 0) {
        double s = 0.0;
#pragma unroll
        for (int i = 0; i < RBLOCK / 64; ++i) s += wred[i];
        out[0] = (float)s;
    }
}

extern "C" void kernel_launch(void* const* d_in, const int* in_sizes, int n_in,
                              void* d_out, int out_size, void* d_ws, size_t ws_size,
                              hipStream_t stream)
{
    const float* outputs = (const float*)d_in[0];
    const float* target  = (const float*)d_in[1];
    float* out = (float*)d_out;
    double* part = (double*)d_ws;   // NCHUNKS doubles = 100352 B

    yolo_loss_kernel<<<NCHUNKS, BLOCK, 0, stream>>>(outputs, target, part);
    reduce_kernel<<<1, RBLOCK, 0, stream>>>(part, out);
}

// Round 12
// 57.869 us; speedup vs baseline: 8.8015x; 1.0620x over previous
//
#include <hip/hip_runtime.h>

// YOLO-style loss, B=131072, GRID=7, CELLS=49, 11 floats/cell.
// FINAL (R12 = R3 restored): the session's optimization ladder:
//   R0  104us  baseline LDS-tiled, single fp64 atomicAdd
//   R2   77us  non-atomic partial-store reduction (atomic was ~15ns/block serial)
//   R3   58.2  CPC=512: 22.5KB LDS, 7 blocks/CU, 28 waves/CU  <- BEST
// Refuted levers (all within 58-63us -> fetch-path ceiling):
//   R4 62.7 persistent+reg-prefetch | R5 59.5 algebraic split (compute not
//   the wall) | R7 62.6 dense f4 stream (LDS/barriers not the wall) |
//   R10 62.3 CPC=256 (occupancy optimum is 512) | R11 61.5 LDS-DMA staging.
//   R8 509us last-block-done: per-block device-scope fences are catastrophic.
// Model: ~141MB HBM + ~142MB L3 per pass at ~600ns mixed latency; sustained
//   4.9 TB/s = ~12KB outstanding/CU = per-CU VMEM request-slot cap (hardware).
//   Compute 30% VALU, LDS 0 conflicts, HBM 2.4/6.3 TB/s -> all slack.
//   This is the roofline for this access pattern.

constexpr int BLOCK = 256;
constexpr int CPC = 512;                        // cells per chunk (per block)
constexpr int FLOATS_PER_CHUNK = CPC * 11;      // 5632
constexpr int F4_PER_CHUNK = FLOATS_PER_CHUNK / 4;  // 1408 = 5.5 * 256
constexpr int TOTAL_CELLS = 131072 * 49;        // 6422528
constexpr int NCHUNKS = TOTAL_CELLS / CPC;      // 12544 (exact)

__global__ __launch_bounds__(BLOCK) void yolo_loss_kernel(
    const float* __restrict__ outputs,
    const float* __restrict__ target,
    double* __restrict__ part)
{
#pragma clang fp contract(off)
    __shared__ float lds[FLOATS_PER_CHUNK];     // 22528 B
    __shared__ double wred[BLOCK / 64];

    const int t = threadIdx.x;
    const unsigned chunk = blockIdx.x;

    // ---- stage 512 cells (1408 float4) into LDS: 5 full rounds + half round
    const float4* src = reinterpret_cast<const float4*>(outputs)
                        + (size_t)chunk * F4_PER_CHUNK;
    float4* l4 = reinterpret_cast<float4*>(lds);
#pragma unroll
    for (int i = 0; i < 5; ++i)
        l4[t + BLOCK * i] = src[t + BLOCK * i];
    if (t < 128)                                 // wave-aligned half round
        l4[t + 1280] = src[t + 1280];
    __syncthreads();

    const float4* tg4 = reinterpret_cast<const float4*>(target);
    const float CW = 1.0f / 7.0f;

    double a = 0.0;
#pragma unroll
    for (int q = 0; q < 2; ++q) {
        const int cl = t + BLOCK * q;               // cell within chunk
        const unsigned g = chunk * CPC + cl;        // global cell index
        const unsigned b = g / 49u;                 // sample
        const unsigned s = g - b * 49u;             // cell within sample
        const float xl = (float)(s % 7u) / 7.0f;    // exact fp32 div, matches numpy
        const float yl = (float)(s / 7u) / 7.0f;

        const float4 T0 = tg4[2u * b];
        const float4 T1 = tg4[2u * b + 1u];
        const bool v1 = (T1.x != -1.0f);

        const float* cp = lds + cl * 11;            // 11t base: coprime w/ 32 banks

        float conf0, conf1, term0, term1;
        bool one0, one1;
        {   // box j=0 (always valid)
            const float px = cp[0], py = cp[1], pw = cp[2], ph = cp[3], pc = cp[4];
            const float tx = T0.x, ty = T0.y, tw = T0.z, th = T0.w;
            const float ix = fabsf(fmaxf(px - 0.5f * pw, tx - 0.5f * tw)
                                 - fminf(px + 0.5f * pw, tx + 0.5f * tw));
            const float iy = fabsf(fmaxf(py - 0.5f * ph, ty - 0.5f * th)
                                 - fminf(py + 0.5f * ph, ty + 0.5f * th));
            const float inter = ix * iy;
            const float uni = pw * ph + tw * th - inter;
            conf0 = inter / uni;
            one0 = (xl <= tx) && (tx <= xl + CW) && (yl <= ty) && (ty <= yl + CW);
            const float d0 = tx - px, d1 = ty - py;
            const float d2 = sqrtf(tw) - sqrtf(pw);
            const float d3 = sqrtf(th) - sqrtf(ph);
            const float coord = ((d0 * d0 + d1 * d1) + d2 * d2) + d3 * d3;
            const float dc = conf0 - pc;
            term0 = one0 ? (5.0f * coord + dc * dc) : (0.5f * pc * pc);
        }
        {   // box j=1 (valid iff T1.x != -1)
            const float px = cp[5], py = cp[6], pw = cp[7], ph = cp[8], pc = cp[9];
            const float tx = T1.x, ty = T1.y, tw = T1.z, th = T1.w;
            const float ix = fabsf(fmaxf(px - 0.5f * pw, tx - 0.5f * tw)
                                 - fminf(px + 0.5f * pw, tx + 0.5f * tw));
            const float iy = fabsf(fmaxf(py - 0.5f * ph, ty - 0.5f * th)
                                 - fminf(py + 0.5f * ph, ty + 0.5f * th));
            const float inter = ix * iy;
            const float uni = pw * ph + tw * th - inter;
            conf1 = inter / uni;
            const bool inx = (xl <= tx) && (tx <= xl + CW);
            const bool iny = (yl <= ty) && (ty <= yl + CW);
            one1 = inx && iny && v1;
            const float d0 = tx - px, d1 = ty - py;
            const float d2 = sqrtf(tw) - sqrtf(pw);
            const float d3 = sqrtf(th) - sqrtf(ph);
            const float coord = ((d0 * d0 + d1 * d1) + d2 * d2) + d3 * d3;
            const float dc = conf1 - pc;
            term1 = one1 ? (5.0f * coord + dc * dc)
                         : (v1 ? (0.5f * pc * pc) : 0.0f);
        }
        // class term
        const float sum_conf = conf0 + (v1 ? conf1 : 0.0f);
        float cls = 0.0f;
        if (one0 || one1) {
            const float d = cp[10] - sum_conf;
            cls = d * d;
        }
        a += (double)term0 + (double)term1 + (double)cls;
    }

    // ---- reduction: wave shfl -> LDS -> block partial -> d_ws (NO atomics)
#pragma unroll
    for (int off = 32; off > 0; off >>= 1)
        a += __shfl_down(a, off);
    if ((t & 63) == 0) wred[t >> 6] = a;
    __syncthreads();
    if (t == 0)
        part[chunk] = wred[0] + wred[1] + wred[2] + wred[3];
}

constexpr int RBLOCK = 1024;
__global__ __launch_bounds__(RBLOCK) void reduce_kernel(
    const double* __restrict__ part, float* __restrict__ out)
{
    __shared__ double wred[RBLOCK / 64];
    const int t = threadIdx.x;
    double a = 0.0;
    for (int i = t; i < NCHUNKS; i += RBLOCK)
        a += part[i];
#pragma unroll
    for (int off = 32; off > 0; off >>= 1)
        a += __shfl_down(a, off);
    if ((t & 63) == 0) wred[t >> 6] = a;
    __syncthreads();
    if (t == 0) {
        double s = 0.0;
#pragma unroll
        for (int i = 0; i < RBLOCK / 64; ++i) s += wred[i];
        out[0] = (float)s;
    }
}

extern "C" void kernel_launch(void* const* d_in, const int* in_sizes, int n_in,
                              void* d_out, int out_size, void* d_ws, size_t ws_size,
                              hipStream_t stream)
{
    const float* outputs = (const float*)d_in[0];
    const float* target  = (const float*)d_in[1];
    float* out = (float*)d_out;
    double* part = (double*)d_ws;   // NCHUNKS doubles = 100352 B

    yolo_loss_kernel<<<NCHUNKS, BLOCK, 0, stream>>>(outputs, target, part);
    reduce_kernel<<<1, RBLOCK, 0, stream>>>(part, out);
}